// Round 4
// baseline (283.670 us; speedup 1.0000x reference)
//
#include <hip/hip_runtime.h>

#define DEVINL __device__ __forceinline__

typedef _Float16 h2  __attribute__((ext_vector_type(2)));
typedef _Float16 h4v __attribute__((ext_vector_type(4)));
typedef _Float16 h8v __attribute__((ext_vector_type(8)));

DEVINL float fexp2(float x){ return __builtin_amdgcn_exp2f(x); }
DEVINL float frcp (float x){ return __builtin_amdgcn_rcpf(x); }

#if __has_builtin(__builtin_amdgcn_fdot2)
DEVINL float dot2(h2 a, h2 b, float c){ return __builtin_amdgcn_fdot2(a, b, c, false); }
#else
DEVINL float dot2(h2 a, h2 b, float c){
  return fmaf((float)a.x, (float)b.x, fmaf((float)a.y, (float)b.y, c));
}
#endif

// ---------------------------------------------------------------------------
// Kernel 1: precompute per-(dir, idx, lane) input-gate table
//   G = { Wr_e·e + bih_r + bhh_r,  Wz_e·e + bih_z + bhh_z,  Wn_e·e + bih_n, 0 }
// plus the static part of out[b].
// ---------------------------------------------------------------------------
template<int H>
DEVINL void pre_entry(int t, const float* __restrict__ emb,
                      const float* __restrict__ Wih_f, const float* __restrict__ bih_f, const float* __restrict__ bhh_f,
                      const float* __restrict__ Wih_b, const float* __restrict__ bih_b, const float* __restrict__ bhh_b,
                      float4* __restrict__ G, int N)
{
  constexpr int E = H - 1;
  const int dir = t / (N * H);
  const int r   = t - dir * (N * H);
  const int idx = r / H;
  const int li  = r - idx * H;
  const float* Wih = dir ? Wih_b : Wih_f;
  const float* bih = dir ? bih_b : bih_f;
  const float* bhh = dir ? bhh_b : bhh_f;
  const float* e = emb + (size_t)idx * E;
  float gr = bih[li]       + bhh[li];
  float gz = bih[H + li]   + bhh[H + li];
  float gn = bih[2*H + li];
#pragma unroll
  for (int q = 0; q < E; q++){
    const float ev = e[q];
    gr = fmaf(Wih[(size_t)( li     )*H + q], ev, gr);
    gz = fmaf(Wih[(size_t)( H + li )*H + q], ev, gz);
    gn = fmaf(Wih[(size_t)(2*H + li)*H + q], ev, gn);
  }
  G[(size_t)(dir * N + idx) * H + li] = make_float4(gr, gz, gn, 0.f);
}

__global__ __launch_bounds__(256) void pre_kernel(
    const float* __restrict__ emb_dp, const float* __restrict__ emb_cp,
    const float* __restrict__ Wih_dpf, const float* __restrict__ bih_dpf, const float* __restrict__ bhh_dpf,
    const float* __restrict__ Wih_dpb, const float* __restrict__ bih_dpb, const float* __restrict__ bhh_dpb,
    const float* __restrict__ Wih_cpf, const float* __restrict__ bih_cpf, const float* __restrict__ bhh_cpf,
    const float* __restrict__ Wih_cpb, const float* __restrict__ bih_cpb, const float* __restrict__ bhh_cpb,
    const float* __restrict__ stat, const float* __restrict__ fc_all_w, const float* __restrict__ fc_all_b,
    const float* __restrict__ fc_dp_b, const float* __restrict__ fc_cp_b,
    float4* __restrict__ Gdp, float4* __restrict__ Gcp, float* __restrict__ out)
{
  constexpr int NDP_E = 2 * 4096 * 9;    // 73728
  constexpr int NCP_E = 2 * 10000 * 11;  // 220000
  const int t = blockIdx.x * 256 + threadIdx.x;
  if (t < NDP_E){
    pre_entry<9>(t, emb_dp, Wih_dpf, bih_dpf, bhh_dpf, Wih_dpb, bih_dpb, bhh_dpb, Gdp, 4096);
  } else if (t < NDP_E + NCP_E){
    pre_entry<11>(t - NDP_E, emb_cp, Wih_cpf, bih_cpf, bhh_cpf, Wih_cpb, bih_cpb, bhh_cpb, Gcp, 10000);
  } else if (t < NDP_E + NCP_E + 4096){
    const int b = t - (NDP_E + NCP_E);
    float s = fc_all_b[0] + fc_all_w[20]*fc_dp_b[0] + fc_all_w[21]*fc_cp_b[0];
    const float* st = stat + (size_t)b * 20;
#pragma unroll
    for (int k = 0; k < 20; k++) s = fmaf(fc_all_w[k], st[k], s);
    out[b] = s;
  }
}

// ---------------------------------------------------------------------------
// Kernel 2: fused GRU, TWO same-direction sequences per lane-group (ILP=2).
// Lane li owns element li of both hidden states; weights/table base shared.
// h broadcast via per-(group,seq) LDS slot, within-wave only (no barriers).
// ---------------------------------------------------------------------------
template<int H, int GPW, int N, int DIR>
DEVINL void gru_pair(int bA, int bB, int li, int slot,
    const int* __restrict__ seq, const float* __restrict__ tim,
    const float4* __restrict__ Gtab,
    const float* __restrict__ Wih, const float* __restrict__ Whh, const float* __restrict__ bhh,
    const float* __restrict__ fc_w, float wt,
    float* __restrict__ out, _Float16* hbuf)
{
  constexpr int S  = 512;
  constexpr int NP = (H + 1) / 2;

  // dt-column weights (f32) and n-gate recurrent bias
  const float Wrd = Wih[( li      )*H + (H-1)];
  const float Wzd = Wih[( H + li  )*H + (H-1)];
  const float Wnd = Wih[(2*H + li )*H + (H-1)];
  const float bhn = bhh[2*H + li];

  // recurrent rows as f16 pairs (pad weight = 0)
  h2 Urp[NP], Uzp[NP], Unp[NP];
#pragma unroll
  for (int j = 0; j < NP; j++){
    const int q0 = 2*j, q1 = 2*j + 1;
    h2 v;
    v.x = (_Float16)Whh[( li      )*H + q0];
    v.y = (_Float16)((q1 < H) ? Whh[( li      )*H + q1] : 0.f);
    Urp[j] = v;
    v.x = (_Float16)Whh[( H + li  )*H + q0];
    v.y = (_Float16)((q1 < H) ? Whh[( H + li  )*H + q1] : 0.f);
    Uzp[j] = v;
    v.x = (_Float16)Whh[(2*H + li )*H + q0];
    v.y = (_Float16)((q1 < H) ? Whh[(2*H + li )*H + q1] : 0.f);
    Unp[j] = v;
  }

  const int gb0 = slot * 48;               // two 24-half slots per pair-group
  const int gb[2] = { gb0, gb0 + 24 };
  if (li == 0){ hbuf[gb[0] + H] = (_Float16)0.f; hbuf[gb[1] + H] = (_Float16)0.f; }

  const int bb2[2] = { bA, bB };
  const int*   sp[2];  const float* tp[2];
#pragma unroll
  for (int s = 0; s < 2; s++){
    sp[s] = seq + (size_t)bb2[s] * S;
    tp[s] = tim + (size_t)bb2[s] * S;
  }
  const char* gbase = (const char*)(Gtab + ((size_t)DIR * N) * H + li);  // shared (same dir)

  h2 hp[2][NP];
#pragma unroll
  for (int s = 0; s < 2; s++)
#pragma unroll
    for (int j = 0; j < NP; j++){ h2 z0; z0.x = (_Float16)0.f; z0.y = (_Float16)0.f; hp[s][j] = z0; }
  float hmine[2] = {0.f, 0.f}, prev[2] = {0.f, 0.f};

  int ic[2][4]; float tc[2][4];
  int icn[2][4] = {{0,0,0,0},{0,0,0,0}}; float tcn[2][4] = {{0,0,0,0},{0,0,0,0}};
#pragma unroll
  for (int s = 0; s < 2; s++){
    const int p0 = DIR ? (S - 4) : 0;
    int4   iv = *reinterpret_cast<const int4*  >(sp[s] + p0);
    float4 tv = *reinterpret_cast<const float4*>(tp[s] + p0);
    if constexpr (DIR){ ic[s][0]=iv.w; ic[s][1]=iv.z; ic[s][2]=iv.y; ic[s][3]=iv.x;
                        tc[s][0]=tv.w; tc[s][1]=tv.z; tc[s][2]=tv.y; tc[s][3]=tv.x; }
    else              { ic[s][0]=iv.x; ic[s][1]=iv.y; ic[s][2]=iv.z; ic[s][3]=iv.w;
                        tc[s][0]=tv.x; tc[s][1]=tv.y; tc[s][2]=tv.z; tc[s][3]=tv.w; }
  }

  // depth-3 gather ring per sequence
  float4 Gb[2][4];
#pragma unroll
  for (int s = 0; s < 2; s++){
    Gb[s][0] = *(const float4*)(gbase + (unsigned)ic[s][0] * (unsigned)(H*16));
    Gb[s][1] = *(const float4*)(gbase + (unsigned)ic[s][1] * (unsigned)(H*16));
    Gb[s][2] = *(const float4*)(gbase + (unsigned)ic[s][2] * (unsigned)(H*16));
  }

#pragma unroll 1
  for (int c = 0; c < S/4; ++c){
    if (c < S/4 - 1){
#pragma unroll
      for (int s = 0; s < 2; s++){
        const int p0 = DIR ? (S - 8 - 4*c) : (4*c + 4);
        int4   iv = *reinterpret_cast<const int4*  >(sp[s] + p0);
        float4 tv = *reinterpret_cast<const float4*>(tp[s] + p0);
        if constexpr (DIR){ icn[s][0]=iv.w; icn[s][1]=iv.z; icn[s][2]=iv.y; icn[s][3]=iv.x;
                            tcn[s][0]=tv.w; tcn[s][1]=tv.z; tcn[s][2]=tv.y; tcn[s][3]=tv.x; }
        else              { icn[s][0]=iv.x; icn[s][1]=iv.y; icn[s][2]=iv.z; icn[s][3]=iv.w;
                            tcn[s][0]=tv.x; tcn[s][1]=tv.y; tcn[s][2]=tv.z; tcn[s][3]=tv.w; }
      }
    }
#pragma unroll
    for (int k = 0; k < 4; k++){
#pragma unroll
      for (int s = 0; s < 2; s++){
        const float4 g4 = Gb[s][k];
        // prefetch step c*4+k+3 (stale icn on last chunk: valid in-range idx, unused)
        {
          const int pidx = (k == 0) ? ic[s][3] : icn[s][k-1];
          Gb[s][(k+3)&3] = *(const float4*)(gbase + (unsigned)pidx * (unsigned)(H*16));
        }
        const float tcur = tc[s][k];
        const float dtv = fmaxf(tcur - prev[s], 0.f); prev[s] = tcur;

        float ar = fmaf(Wrd, dtv, g4.x);
        float az = fmaf(Wzd, dtv, g4.y);
        float an = fmaf(Wnd, dtv, g4.z);
        float hn = bhn;
#pragma unroll
        for (int j = 0; j < NP; j++){
          ar = dot2(Urp[j], hp[s][j], ar);
          az = dot2(Uzp[j], hp[s][j], az);
          hn = dot2(Unp[j], hp[s][j], hn);
        }
        const float r  = frcp(1.f + fexp2(-1.4426950408889634f * ar));
        const float z  = frcp(1.f + fexp2(-1.4426950408889634f * az));
        const float ec = fexp2(2.885390081777927f * fmaf(r, hn, an));
        const float n  = fmaf(-2.f, frcp(1.f + ec), 1.f);
        hmine[s] = fmaf(z, hmine[s] - n, n);       // (1-z)*n + z*h

        hbuf[gb[s] + li] = (_Float16)hmine[s];     // publish own element (2B)
      }
      __builtin_amdgcn_wave_barrier();
      asm volatile("" ::: "memory");               // in-order DS pipe: writes land before reads
#pragma unroll
      for (int s = 0; s < 2; s++){
        h8v hv = *reinterpret_cast<const h8v*>(hbuf + gb[s]);
        hp[s][0] = __builtin_shufflevector(hv, hv, 0, 1);
        hp[s][1] = __builtin_shufflevector(hv, hv, 2, 3);
        hp[s][2] = __builtin_shufflevector(hv, hv, 4, 5);
        hp[s][3] = __builtin_shufflevector(hv, hv, 6, 7);
        if constexpr (H == 9){
          hp[s][4] = *reinterpret_cast<const h2*>(hbuf + gb[s] + 8);
        } else {
          h4v t4 = *reinterpret_cast<const h4v*>(hbuf + gb[s] + 8);
          hp[s][4] = __builtin_shufflevector(t4, t4, 0, 1);
          hp[s][5] = __builtin_shufflevector(t4, t4, 2, 3);
        }
      }
    }
#pragma unroll
    for (int s = 0; s < 2; s++)
#pragma unroll
      for (int k2 = 0; k2 < 4; k2++){ ic[s][k2] = icn[s][k2]; tc[s][k2] = tcn[s][k2]; }
  }

  // one atomic per sequence (lane 0 holds the full h in hp)
  if (li == 0){
#pragma unroll
    for (int s = 0; s < 2; s++){
      float dot = 0.f;
#pragma unroll
      for (int j = 0; j < NP; j++){
        dot = fmaf(fc_w[DIR*H + 2*j], (float)hp[s][j].x, dot);
        if (2*j + 1 < H) dot = fmaf(fc_w[DIR*H + 2*j + 1], (float)hp[s][j].y, dot);
      }
      atomicAdd(out + bb2[s], wt * dot);
    }
  }
}

__global__ __launch_bounds__(256, 2) void gru_fused(
    const int* __restrict__ dp,  const float* __restrict__ dp_t,
    const int* __restrict__ cp,  const float* __restrict__ cp_t,
    const float4* __restrict__ Gdp, const float4* __restrict__ Gcp,
    const float* __restrict__ Wih_dpf, const float* __restrict__ Whh_dpf, const float* __restrict__ bhh_dpf,
    const float* __restrict__ Wih_dpb, const float* __restrict__ Whh_dpb, const float* __restrict__ bhh_dpb,
    const float* __restrict__ Wih_cpf, const float* __restrict__ Whh_cpf, const float* __restrict__ bhh_cpf,
    const float* __restrict__ Wih_cpb, const float* __restrict__ Whh_cpb, const float* __restrict__ bhh_cpb,
    const float* __restrict__ fc_dp_w, const float* __restrict__ fc_cp_w, const float* __restrict__ fc_all_w,
    float* __restrict__ out, int DP_BLOCKS)
{
  __shared__ __align__(16) _Float16 hbuf[28*48 + 8];
  const int tid = threadIdx.x, wave = tid >> 6, lane = tid & 63;

  if ((int)blockIdx.x < DP_BLOCKS){
    constexpr int H = 9, GPW = 7;
    const int g = lane / H;
    if (g >= GPW) return;
    const int li   = lane - g * H;
    const int pair = blockIdx.x * (4*GPW) + wave * GPW + g;
    if (pair >= 4096) return;
    const int slot = wave * GPW + g;
    const int gidA = 2*pair;
    const int bA = gidA & 4095, bB = (gidA + 1) & 4095;
    const float wt = fc_all_w[20];
    if ((gidA >> 12) == 0)
      gru_pair<9,7,4096,0>(bA, bB, li, slot, dp, dp_t, Gdp, Wih_dpf, Whh_dpf, bhh_dpf, fc_dp_w, wt, out, hbuf);
    else
      gru_pair<9,7,4096,1>(bA, bB, li, slot, dp, dp_t, Gdp, Wih_dpb, Whh_dpb, bhh_dpb, fc_dp_w, wt, out, hbuf);
  } else {
    constexpr int H = 11, GPW = 5;
    const int blk = blockIdx.x - DP_BLOCKS;
    const int g = lane / H;
    if (g >= GPW) return;
    const int li   = lane - g * H;
    const int pair = blk * (4*GPW) + wave * GPW + g;
    if (pair >= 4096) return;
    const int slot = wave * GPW + g;
    const int gidA = 2*pair;
    const int bA = gidA & 4095, bB = (gidA + 1) & 4095;
    const float wt = fc_all_w[21];
    if ((gidA >> 12) == 0)
      gru_pair<11,5,10000,0>(bA, bB, li, slot, cp, cp_t, Gcp, Wih_cpf, Whh_cpf, bhh_cpf, fc_cp_w, wt, out, hbuf);
    else
      gru_pair<11,5,10000,1>(bA, bB, li, slot, cp, cp_t, Gcp, Wih_cpb, Whh_cpb, bhh_cpb, fc_cp_w, wt, out, hbuf);
  }
}

extern "C" void kernel_launch(void* const* d_in, const int* in_sizes, int n_in,
                              void* d_out, int out_size, void* d_ws, size_t ws_size,
                              hipStream_t stream)
{
  const float* stat   = (const float*)d_in[0];
  const int*   dp     = (const int*)  d_in[1];
  const int*   cp     = (const int*)  d_in[2];
  const float* dp_t   = (const float*)d_in[3];
  const float* cp_t   = (const float*)d_in[4];
  const float* emb_dp = (const float*)d_in[5];
  const float* emb_cp = (const float*)d_in[6];

  const float* Wih_dpf = (const float*)d_in[7];
  const float* Whh_dpf = (const float*)d_in[8];
  const float* bih_dpf = (const float*)d_in[9];
  const float* bhh_dpf = (const float*)d_in[10];
  const float* Wih_dpb = (const float*)d_in[11];
  const float* Whh_dpb = (const float*)d_in[12];
  const float* bih_dpb = (const float*)d_in[13];
  const float* bhh_dpb = (const float*)d_in[14];
  const float* Wih_cpf = (const float*)d_in[15];
  const float* Whh_cpf = (const float*)d_in[16];
  const float* bih_cpf = (const float*)d_in[17];
  const float* bhh_cpf = (const float*)d_in[18];
  const float* Wih_cpb = (const float*)d_in[19];
  const float* Whh_cpb = (const float*)d_in[20];
  const float* bih_cpb = (const float*)d_in[21];
  const float* bhh_cpb = (const float*)d_in[22];

  const float* fc_dp_w  = (const float*)d_in[23];
  const float* fc_dp_b  = (const float*)d_in[24];
  const float* fc_cp_w  = (const float*)d_in[25];
  const float* fc_cp_b  = (const float*)d_in[26];
  const float* fc_all_w = (const float*)d_in[27];
  const float* fc_all_b = (const float*)d_in[28];

  float* out = (float*)d_out;

  // workspace: dp table (2*4096*9 float4 = 1.18 MB), cp table (2*10000*11 float4 = 3.52 MB)
  float4* Gdp = (float4*)d_ws;
  float4* Gcp = (float4*)((char*)d_ws + (size_t)(2*4096*9) * sizeof(float4));

  {
    const int total = 2*4096*9 + 2*10000*11 + 4096;
    const int blocks = (total + 255) / 256;
    pre_kernel<<<blocks, 256, 0, stream>>>(
        emb_dp, emb_cp,
        Wih_dpf, bih_dpf, bhh_dpf, Wih_dpb, bih_dpb, bhh_dpb,
        Wih_cpf, bih_cpf, bhh_cpf, Wih_cpb, bih_cpb, bhh_cpb,
        stat, fc_all_w, fc_all_b, fc_dp_b, fc_cp_b,
        Gdp, Gcp, out);
  }

  {
    const int DP_BLOCKS = (4096 + 27) / 28;   // H=9,  7 pairs/wave
    const int CP_BLOCKS = (4096 + 19) / 20;   // H=11, 5 pairs/wave
    gru_fused<<<DP_BLOCKS + CP_BLOCKS, 256, 0, stream>>>(
        dp, dp_t, cp, cp_t, Gdp, Gcp,
        Wih_dpf, Whh_dpf, bhh_dpf, Wih_dpb, Whh_dpb, bhh_dpb,
        Wih_cpf, Whh_cpf, bhh_cpf, Wih_cpb, Whh_cpb, bhh_cpb,
        fc_dp_w, fc_cp_w, fc_all_w, out, DP_BLOCKS);
  }
}

// Round 5
// 231.480 us; speedup vs baseline: 1.2255x; 1.2255x over previous
//
#include <hip/hip_runtime.h>

#define DEVINL __device__ __forceinline__

typedef _Float16 h4v __attribute__((ext_vector_type(4)));

DEVINL float fexp2(float x){ return __builtin_amdgcn_exp2f(x); }
DEVINL float frcp (float x){ return __builtin_amdgcn_rcpf(x); }

// ---------------------------------------------------------------------------
// Kernel 1: precompute per-(dir, idx, lane) input-gate table, packed f16:
//   G = { Wr_e·e + bih_r + bhh_r,  Wz_e·e + bih_z + bhh_z,  Wn_e·e + bih_n, 0 }
// 8 B per entry -> dp table 0.59 MB + cp table 1.76 MB = 2.35 MB (L2-resident).
// Plus the static part of out[b].
// ---------------------------------------------------------------------------
template<int H>
DEVINL void pre_entry(int t, const float* __restrict__ emb,
                      const float* __restrict__ Wih_f, const float* __restrict__ bih_f, const float* __restrict__ bhh_f,
                      const float* __restrict__ Wih_b, const float* __restrict__ bih_b, const float* __restrict__ bhh_b,
                      h4v* __restrict__ G, int N)
{
  constexpr int E = H - 1;
  const int dir = t / (N * H);
  const int r   = t - dir * (N * H);
  const int idx = r / H;
  const int li  = r - idx * H;
  const float* Wih = dir ? Wih_b : Wih_f;
  const float* bih = dir ? bih_b : bih_f;
  const float* bhh = dir ? bhh_b : bhh_f;
  const float* e = emb + (size_t)idx * E;
  float gr = bih[li]       + bhh[li];
  float gz = bih[H + li]   + bhh[H + li];
  float gn = bih[2*H + li];
#pragma unroll
  for (int q = 0; q < E; q++){
    const float ev = e[q];
    gr = fmaf(Wih[(size_t)( li     )*H + q], ev, gr);
    gz = fmaf(Wih[(size_t)( H + li )*H + q], ev, gz);
    gn = fmaf(Wih[(size_t)(2*H + li)*H + q], ev, gn);
  }
  h4v g;
  g.x = (_Float16)gr; g.y = (_Float16)gz; g.z = (_Float16)gn; g.w = (_Float16)0.f;
  G[(size_t)(dir * N + idx) * H + li] = g;
}

__global__ __launch_bounds__(256) void pre_kernel(
    const float* __restrict__ emb_dp, const float* __restrict__ emb_cp,
    const float* __restrict__ Wih_dpf, const float* __restrict__ bih_dpf, const float* __restrict__ bhh_dpf,
    const float* __restrict__ Wih_dpb, const float* __restrict__ bih_dpb, const float* __restrict__ bhh_dpb,
    const float* __restrict__ Wih_cpf, const float* __restrict__ bih_cpf, const float* __restrict__ bhh_cpf,
    const float* __restrict__ Wih_cpb, const float* __restrict__ bih_cpb, const float* __restrict__ bhh_cpb,
    const float* __restrict__ stat, const float* __restrict__ fc_all_w, const float* __restrict__ fc_all_b,
    const float* __restrict__ fc_dp_b, const float* __restrict__ fc_cp_b,
    h4v* __restrict__ Gdp, h4v* __restrict__ Gcp, float* __restrict__ out)
{
  constexpr int NDP_E = 2 * 4096 * 9;    // 73728
  constexpr int NCP_E = 2 * 10000 * 11;  // 220000
  const int t = blockIdx.x * 256 + threadIdx.x;
  if (t < NDP_E){
    pre_entry<9>(t, emb_dp, Wih_dpf, bih_dpf, bhh_dpf, Wih_dpb, bih_dpb, bhh_dpb, Gdp, 4096);
  } else if (t < NDP_E + NCP_E){
    pre_entry<11>(t - NDP_E, emb_cp, Wih_cpf, bih_cpf, bhh_cpf, Wih_cpb, bih_cpb, bhh_cpb, Gcp, 10000);
  } else if (t < NDP_E + NCP_E + 4096){
    const int b = t - (NDP_E + NCP_E);
    float s = fc_all_b[0] + fc_all_w[20]*fc_dp_b[0] + fc_all_w[21]*fc_cp_b[0];
    const float* st = stat + (size_t)b * 20;
#pragma unroll
    for (int k = 0; k < 20; k++) s = fmaf(fc_all_w[k], st[k], s);
    out[b] = s;
  }
}

// ---------------------------------------------------------------------------
// Kernel 2: fused GRU (round-2 structure). Group of H lanes per sequence.
// f32 gate math, f32 h broadcast via per-group LDS slot (within-wave, no
// barriers), f16 G-table gather with depth-3 ring prefetch, DIR compile-time.
// ---------------------------------------------------------------------------
template<int H, int GPW, int N, int DIR>
DEVINL void gru_run(int gid, int li, int slot,
    const int* __restrict__ seq, const float* __restrict__ tim,
    const h4v* __restrict__ Gtab,
    const float* __restrict__ Wih, const float* __restrict__ Whh, const float* __restrict__ bhh,
    const float* __restrict__ fc_w, float wt,
    float* __restrict__ out, float* hbuf)
{
  constexpr int S = 512;
  const int b = gid & 4095;

  // dt-column weights (f32) and n-gate recurrent bias
  const float Wrd = Wih[( li      )*H + (H-1)];
  const float Wzd = Wih[( H + li  )*H + (H-1)];
  const float Wnd = Wih[(2*H + li )*H + (H-1)];
  const float bhn = bhh[2*H + li];

  float Ur[H], Uz[H], Un[H];
#pragma unroll
  for (int k = 0; k < H; k++){
    Ur[k] = Whh[( li      )*H + k];
    Uz[k] = Whh[( H + li  )*H + k];
    Un[k] = Whh[(2*H + li )*H + k];
  }

  const int*   sp = seq + (size_t)b * S;
  const float* tp = tim + (size_t)b * S;
  const char*  gbase = (const char*)(Gtab + ((size_t)DIR * N) * H + li);

  float h[H];
#pragma unroll
  for (int k = 0; k < H; k++) h[k] = 0.f;
  float hmine = 0.f, prev = 0.f;

  const int gb = slot * 20;   // float offset of group slot (80B stride: b128-disjoint)

  int ic[4]; float tc[4];
  int icn[4] = {0,0,0,0}; float tcn[4] = {0,0,0,0};
  {
    const int p0 = DIR ? (S - 4) : 0;
    int4   iv = *reinterpret_cast<const int4*  >(sp + p0);
    float4 tv = *reinterpret_cast<const float4*>(tp + p0);
    if constexpr (DIR){ ic[0]=iv.w; ic[1]=iv.z; ic[2]=iv.y; ic[3]=iv.x;
                        tc[0]=tv.w; tc[1]=tv.z; tc[2]=tv.y; tc[3]=tv.x; }
    else              { ic[0]=iv.x; ic[1]=iv.y; ic[2]=iv.z; ic[3]=iv.w;
                        tc[0]=tv.x; tc[1]=tv.y; tc[2]=tv.z; tc[3]=tv.w; }
  }

  // depth-3 gather ring (8B f16 rows)
  h4v Gb[4];
  Gb[0] = *(const h4v*)(gbase + (unsigned)ic[0] * (unsigned)(H*8));
  Gb[1] = *(const h4v*)(gbase + (unsigned)ic[1] * (unsigned)(H*8));
  Gb[2] = *(const h4v*)(gbase + (unsigned)ic[2] * (unsigned)(H*8));

#pragma unroll 1
  for (int c = 0; c < S/4; ++c){
    if (c < S/4 - 1){
      const int p0 = DIR ? (S - 8 - 4*c) : (4*c + 4);
      int4   iv = *reinterpret_cast<const int4*  >(sp + p0);
      float4 tv = *reinterpret_cast<const float4*>(tp + p0);
      if constexpr (DIR){ icn[0]=iv.w; icn[1]=iv.z; icn[2]=iv.y; icn[3]=iv.x;
                          tcn[0]=tv.w; tcn[1]=tv.z; tcn[2]=tv.y; tcn[3]=tv.x; }
      else              { icn[0]=iv.x; icn[1]=iv.y; icn[2]=iv.z; icn[3]=iv.w;
                          tcn[0]=tv.x; tcn[1]=tv.y; tcn[2]=tv.z; tcn[3]=tv.w; }
    }
#pragma unroll
    for (int k = 0; k < 4; k++){
      const h4v g4 = Gb[k];
      // prefetch step c*4+k+3 (stale icn on last chunk: valid in-range idx, unused)
      {
        const int pidx = (k == 0) ? ic[3] : icn[k-1];
        Gb[(k+3)&3] = *(const h4v*)(gbase + (unsigned)pidx * (unsigned)(H*8));
      }

      const float tcur = tc[k];
      const float dtv = fmaxf(tcur - prev, 0.f); prev = tcur;

      float ar0 = fmaf(Wrd, dtv, (float)g4.x), ar1 = 0.f;
      float az0 = fmaf(Wzd, dtv, (float)g4.y), az1 = 0.f;
      float an  = fmaf(Wnd, dtv, (float)g4.z);
      float hn0 = bhn, hn1 = 0.f;
#pragma unroll
      for (int q = 0; q < H; q += 2){
        ar0 = fmaf(Ur[q], h[q], ar0);
        az0 = fmaf(Uz[q], h[q], az0);
        hn0 = fmaf(Un[q], h[q], hn0);
      }
#pragma unroll
      for (int q = 1; q < H; q += 2){
        ar1 = fmaf(Ur[q], h[q], ar1);
        az1 = fmaf(Uz[q], h[q], az1);
        hn1 = fmaf(Un[q], h[q], hn1);
      }
      const float r  = frcp(1.f + fexp2(-1.4426950408889634f * (ar0 + ar1)));
      const float z  = frcp(1.f + fexp2(-1.4426950408889634f * (az0 + az1)));
      const float ec = fexp2(2.885390081777927f * fmaf(r, hn0 + hn1, an));
      const float n  = fmaf(-2.f, frcp(1.f + ec), 1.f);
      hmine = fmaf(z, hmine - n, n);            // (1-z)*n + z*h

      hbuf[gb + li] = hmine;                    // publish own element
      __builtin_amdgcn_wave_barrier();
      asm volatile("" ::: "memory");            // in-order DS pipe: write lands before reads

      float4 h03 = *reinterpret_cast<const float4*>(&hbuf[gb]);
      float4 h47 = *reinterpret_cast<const float4*>(&hbuf[gb+4]);
      h[0]=h03.x; h[1]=h03.y; h[2]=h03.z; h[3]=h03.w;
      h[4]=h47.x; h[5]=h47.y; h[6]=h47.z; h[7]=h47.w;
      if constexpr (H == 9){
        h[8] = hbuf[gb+8];
      } else {
        float4 h8b = *reinterpret_cast<const float4*>(&hbuf[gb+8]);
        h[8]=h8b.x; h[9]=h8b.y; h[10]=h8b.z;
      }
    }
#pragma unroll
    for (int k2 = 0; k2 < 4; k2++){ ic[k2] = icn[k2]; tc[k2] = tcn[k2]; }
  }

  // one atomic per sequence (lane 0 holds the full final h)
  if (li == 0){
    float dot = 0.f;
#pragma unroll
    for (int q = 0; q < H; q++) dot = fmaf(fc_w[DIR*H + q], h[q], dot);
    atomicAdd(out + b, wt * dot);
  }
}

__global__ __launch_bounds__(256) void gru_fused(
    const int* __restrict__ dp,  const float* __restrict__ dp_t,
    const int* __restrict__ cp,  const float* __restrict__ cp_t,
    const h4v* __restrict__ Gdp, const h4v* __restrict__ Gcp,
    const float* __restrict__ Wih_dpf, const float* __restrict__ Whh_dpf, const float* __restrict__ bhh_dpf,
    const float* __restrict__ Wih_dpb, const float* __restrict__ Whh_dpb, const float* __restrict__ bhh_dpb,
    const float* __restrict__ Wih_cpf, const float* __restrict__ Whh_cpf, const float* __restrict__ bhh_cpf,
    const float* __restrict__ Wih_cpb, const float* __restrict__ Whh_cpb, const float* __restrict__ bhh_cpb,
    const float* __restrict__ fc_dp_w, const float* __restrict__ fc_cp_w, const float* __restrict__ fc_all_w,
    float* __restrict__ out, int DP_BLOCKS)
{
  __shared__ __align__(16) float hbuf[28 * 20];
  const int tid = threadIdx.x, wave = tid >> 6, lane = tid & 63;

  if ((int)blockIdx.x < DP_BLOCKS){
    constexpr int H = 9, GPW = 7;
    const int g = lane / H;
    if (g >= GPW) return;
    const int li  = lane - g * H;
    const int gid = blockIdx.x * (4*GPW) + wave * GPW + g;
    if (gid >= 8192) return;
    const int slot = wave * GPW + g;
    const float wt = fc_all_w[20];
    if ((gid >> 12) == 0)
      gru_run<9,7,4096,0>(gid, li, slot, dp, dp_t, Gdp, Wih_dpf, Whh_dpf, bhh_dpf, fc_dp_w, wt, out, hbuf);
    else
      gru_run<9,7,4096,1>(gid, li, slot, dp, dp_t, Gdp, Wih_dpb, Whh_dpb, bhh_dpb, fc_dp_w, wt, out, hbuf);
  } else {
    constexpr int H = 11, GPW = 5;
    const int blk = blockIdx.x - DP_BLOCKS;
    const int g = lane / H;
    if (g >= GPW) return;
    const int li  = lane - g * H;
    const int gid = blk * (4*GPW) + wave * GPW + g;
    if (gid >= 8192) return;
    const int slot = wave * GPW + g;
    const float wt = fc_all_w[21];
    if ((gid >> 12) == 0)
      gru_run<11,5,10000,0>(gid, li, slot, cp, cp_t, Gcp, Wih_cpf, Whh_cpf, bhh_cpf, fc_cp_w, wt, out, hbuf);
    else
      gru_run<11,5,10000,1>(gid, li, slot, cp, cp_t, Gcp, Wih_cpb, Whh_cpb, bhh_cpb, fc_cp_w, wt, out, hbuf);
  }
}

extern "C" void kernel_launch(void* const* d_in, const int* in_sizes, int n_in,
                              void* d_out, int out_size, void* d_ws, size_t ws_size,
                              hipStream_t stream)
{
  const float* stat   = (const float*)d_in[0];
  const int*   dp     = (const int*)  d_in[1];
  const int*   cp     = (const int*)  d_in[2];
  const float* dp_t   = (const float*)d_in[3];
  const float* cp_t   = (const float*)d_in[4];
  const float* emb_dp = (const float*)d_in[5];
  const float* emb_cp = (const float*)d_in[6];

  const float* Wih_dpf = (const float*)d_in[7];
  const float* Whh_dpf = (const float*)d_in[8];
  const float* bih_dpf = (const float*)d_in[9];
  const float* bhh_dpf = (const float*)d_in[10];
  const float* Wih_dpb = (const float*)d_in[11];
  const float* Whh_dpb = (const float*)d_in[12];
  const float* bih_dpb = (const float*)d_in[13];
  const float* bhh_dpb = (const float*)d_in[14];
  const float* Wih_cpf = (const float*)d_in[15];
  const float* Whh_cpf = (const float*)d_in[16];
  const float* bih_cpf = (const float*)d_in[17];
  const float* bhh_cpf = (const float*)d_in[18];
  const float* Wih_cpb = (const float*)d_in[19];
  const float* Whh_cpb = (const float*)d_in[20];
  const float* bih_cpb = (const float*)d_in[21];
  const float* bhh_cpb = (const float*)d_in[22];

  const float* fc_dp_w  = (const float*)d_in[23];
  const float* fc_dp_b  = (const float*)d_in[24];
  const float* fc_cp_w  = (const float*)d_in[25];
  const float* fc_cp_b  = (const float*)d_in[26];
  const float* fc_all_w = (const float*)d_in[27];
  const float* fc_all_b = (const float*)d_in[28];

  float* out = (float*)d_out;

  // workspace: dp table (2*4096*9 * 8B = 0.59 MB), cp table (2*10000*11 * 8B = 1.76 MB)
  h4v* Gdp = (h4v*)d_ws;
  h4v* Gcp = (h4v*)((char*)d_ws + (size_t)(2*4096*9) * sizeof(h4v));

  {
    const int total = 2*4096*9 + 2*10000*11 + 4096;
    const int blocks = (total + 255) / 256;
    pre_kernel<<<blocks, 256, 0, stream>>>(
        emb_dp, emb_cp,
        Wih_dpf, bih_dpf, bhh_dpf, Wih_dpb, bih_dpb, bhh_dpb,
        Wih_cpf, bih_cpf, bhh_cpf, Wih_cpb, bih_cpb, bhh_cpb,
        stat, fc_all_w, fc_all_b, fc_dp_b, fc_cp_b,
        Gdp, Gcp, out);
  }

  {
    const int DP_BLOCKS = (8192 + 27) / 28;   // H=9,  7 groups/wave
    const int CP_BLOCKS = (8192 + 19) / 20;   // H=11, 5 groups/wave
    gru_fused<<<DP_BLOCKS + CP_BLOCKS, 256, 0, stream>>>(
        dp, dp_t, cp, cp_t, Gdp, Gcp,
        Wih_dpf, Whh_dpf, bhh_dpf, Wih_dpb, Whh_dpb, bhh_dpb,
        Wih_cpf, Whh_cpf, bhh_cpf, Wih_cpb, Whh_cpb, bhh_cpb,
        fc_dp_w, fc_cp_w, fc_all_w, out, DP_BLOCKS);
  }
}

// Round 6
// 187.311 us; speedup vs baseline: 1.5144x; 1.2358x over previous
//
#include <hip/hip_runtime.h>

#define DEVINL __device__ __forceinline__

typedef float f32x2 __attribute__((ext_vector_type(2)));

DEVINL float fexp2(float x){ return __builtin_amdgcn_exp2f(x); }
DEVINL float frcp (float x){ return __builtin_amdgcn_rcpf(x); }

#define LOG2E 1.4426950408889634f

// ---------------------------------------------------------------------------
// Kernel 1: precompute per-(dir, idx, lane) input-gate table, PRE-SCALED:
//   G = { -log2e * (Wr_e·e + bih_r + bhh_r),
//         -log2e * (Wz_e·e + bih_z + bhh_z),
//         2*log2e * (Wn_e·e + bih_n), 0 }
// so the gate math needs no explicit log2e multiplies.
// Plus the static part of out[b].
// ---------------------------------------------------------------------------
template<int H>
DEVINL void pre_entry(int t, const float* __restrict__ emb,
                      const float* __restrict__ Wih_f, const float* __restrict__ bih_f, const float* __restrict__ bhh_f,
                      const float* __restrict__ Wih_b, const float* __restrict__ bih_b, const float* __restrict__ bhh_b,
                      float4* __restrict__ G, int N)
{
  constexpr int E = H - 1;
  const int dir = t / (N * H);
  const int r   = t - dir * (N * H);
  const int idx = r / H;
  const int li  = r - idx * H;
  const float* Wih = dir ? Wih_b : Wih_f;
  const float* bih = dir ? bih_b : bih_f;
  const float* bhh = dir ? bhh_b : bhh_f;
  const float* e = emb + (size_t)idx * E;
  float gr = bih[li]       + bhh[li];
  float gz = bih[H + li]   + bhh[H + li];
  float gn = bih[2*H + li];
#pragma unroll
  for (int q = 0; q < E; q++){
    const float ev = e[q];
    gr = fmaf(Wih[(size_t)( li     )*H + q], ev, gr);
    gz = fmaf(Wih[(size_t)( H + li )*H + q], ev, gz);
    gn = fmaf(Wih[(size_t)(2*H + li)*H + q], ev, gn);
  }
  G[(size_t)(dir * N + idx) * H + li] =
      make_float4(-LOG2E * gr, -LOG2E * gz, 2.f * LOG2E * gn, 0.f);
}

__global__ __launch_bounds__(256) void pre_kernel(
    const float* __restrict__ emb_dp, const float* __restrict__ emb_cp,
    const float* __restrict__ Wih_dpf, const float* __restrict__ bih_dpf, const float* __restrict__ bhh_dpf,
    const float* __restrict__ Wih_dpb, const float* __restrict__ bih_dpb, const float* __restrict__ bhh_dpb,
    const float* __restrict__ Wih_cpf, const float* __restrict__ bih_cpf, const float* __restrict__ bhh_cpf,
    const float* __restrict__ Wih_cpb, const float* __restrict__ bih_cpb, const float* __restrict__ bhh_cpb,
    const float* __restrict__ stat, const float* __restrict__ fc_all_w, const float* __restrict__ fc_all_b,
    const float* __restrict__ fc_dp_b, const float* __restrict__ fc_cp_b,
    float4* __restrict__ Gdp, float4* __restrict__ Gcp, float* __restrict__ out)
{
  constexpr int NDP_E = 2 * 4096 * 9;    // 73728
  constexpr int NCP_E = 2 * 10000 * 11;  // 220000
  const int t = blockIdx.x * 256 + threadIdx.x;
  if (t < NDP_E){
    pre_entry<9>(t, emb_dp, Wih_dpf, bih_dpf, bhh_dpf, Wih_dpb, bih_dpb, bhh_dpb, Gdp, 4096);
  } else if (t < NDP_E + NCP_E){
    pre_entry<11>(t - NDP_E, emb_cp, Wih_cpf, bih_cpf, bhh_cpf, Wih_cpb, bih_cpb, bhh_cpb, Gcp, 10000);
  } else if (t < NDP_E + NCP_E + 4096){
    const int b = t - (NDP_E + NCP_E);
    float s = fc_all_b[0] + fc_all_w[20]*fc_dp_b[0] + fc_all_w[21]*fc_cp_b[0];
    const float* st = stat + (size_t)b * 20;
#pragma unroll
    for (int k = 0; k < 20; k++) s = fmaf(fc_all_w[k], st[k], s);
    out[b] = s;
  }
}

// ---------------------------------------------------------------------------
// Kernel 2: fused GRU — r2 skeleton (single code path, runtime dir, f32 table,
// depth-2 ring, f32 LDS h-broadcast, one atomic/group) with busy-cycle cuts:
// pre-scaled gates, v_pk_fma_f32 pair-dots, shared rcp for r/z.
// ---------------------------------------------------------------------------
template<int H, int GPW, int N>
DEVINL void gru_body(int blk,
    const int*   __restrict__ seq,  const float* __restrict__ tim,
    const float4* __restrict__ Gtab,
    const float* __restrict__ Wih_f, const float* __restrict__ Whh_f, const float* __restrict__ bhh_f,
    const float* __restrict__ Wih_b, const float* __restrict__ Whh_b, const float* __restrict__ bhh_b,
    const float* __restrict__ fc_w, const float* __restrict__ fc_all_w, int tail_idx,
    float* __restrict__ out, float* hbuf)
{
  constexpr int S   = 512;
  constexpr int GPB = 4 * GPW;
  constexpr int NP  = (H + 1) / 2;

  const int tid  = threadIdx.x;
  const int wave = tid >> 6, lane = tid & 63;
  const int g_in_wave = lane / H;
  const int li = lane - g_in_wave * H;
  if (g_in_wave >= GPW) return;
  const int gid = blk * GPB + wave * GPW + g_in_wave;
  if (gid >= 8192) return;
  const int b   = gid & 4095;
  const int dir = gid >> 12;

  const float* Wih = dir ? Wih_b : Wih_f;
  const float* Whh = dir ? Whh_b : Whh_f;

  // dt-column weights and recurrent rows, pre-scaled; packed as f32x2 pairs
  const float Wrd = -LOG2E      * Wih[( li      )*H + (H-1)];
  const float Wzd = -LOG2E      * Wih[( H + li  )*H + (H-1)];
  const float Wnd = 2.f * LOG2E * Wih[(2*H + li )*H + (H-1)];
  f32x2 Urp[NP], Uzp[NP], Unp[NP];
#pragma unroll
  for (int j = 0; j < NP; j++){
    const int q0 = 2*j, q1 = 2*j + 1;
    f32x2 v;
    v.x = -LOG2E * Whh[( li      )*H + q0];
    v.y = (q1 < H) ? -LOG2E * Whh[( li      )*H + q1] : 0.f;
    Urp[j] = v;
    v.x = -LOG2E * Whh[( H + li  )*H + q0];
    v.y = (q1 < H) ? -LOG2E * Whh[( H + li  )*H + q1] : 0.f;
    Uzp[j] = v;
    v.x = 2.f * LOG2E * Whh[(2*H + li )*H + q0];
    v.y = (q1 < H) ? 2.f * LOG2E * Whh[(2*H + li )*H + q1] : 0.f;
    Unp[j] = v;
  }
  const float bhn = 2.f * LOG2E * (dir ? bhh_b : bhh_f)[2*H + li];

  const int*    sp = seq + (size_t)b * S;
  const float*  tp = tim + (size_t)b * S;
  const float4* pG = Gtab + (size_t)(dir * N) * H + li;   // + idx*H per step

  const int gb = (wave * GPW + g_in_wave) * 20;   // 80B slot stride
  if (li == 0) hbuf[gb + H] = 0.f;                // zero the pad element read by last pair

  f32x2 hp[NP];
#pragma unroll
  for (int j = 0; j < NP; j++){ f32x2 z0; z0.x = 0.f; z0.y = 0.f; hp[j] = z0; }
  float h_final[H];                               // kept only for the tail dot (updated each step)
#pragma unroll
  for (int k = 0; k < H; k++) h_final[k] = 0.f;
  float hmine = 0.f, prev = 0.f;

  int ic[4]; float tc[4];
  int icn[4] = {0,0,0,0}; float tcn[4] = {0,0,0,0};
  {
    const int p0 = dir ? (S - 4) : 0;
    int4   iv = *reinterpret_cast<const int4*  >(sp + p0);
    float4 tv = *reinterpret_cast<const float4*>(tp + p0);
    if (dir){ ic[0]=iv.w; ic[1]=iv.z; ic[2]=iv.y; ic[3]=iv.x;
              tc[0]=tv.w; tc[1]=tv.z; tc[2]=tv.y; tc[3]=tv.x; }
    else    { ic[0]=iv.x; ic[1]=iv.y; ic[2]=iv.z; ic[3]=iv.w;
              tc[0]=tv.x; tc[1]=tv.y; tc[2]=tv.z; tc[3]=tv.w; }
  }

  // depth-2 gather ring (r2-proven)
  float4 Gb[4];
  Gb[0] = pG[(size_t)ic[0] * H];
  Gb[1] = pG[(size_t)ic[1] * H];

#pragma unroll 1
  for (int c = 0; c < S/4; ++c){
    if (c < S/4 - 1){
      const int p0 = dir ? (S - 8 - 4*c) : (4*c + 4);
      int4   iv = *reinterpret_cast<const int4*  >(sp + p0);
      float4 tv = *reinterpret_cast<const float4*>(tp + p0);
      if (dir){ icn[0]=iv.w; icn[1]=iv.z; icn[2]=iv.y; icn[3]=iv.x;
                tcn[0]=tv.w; tcn[1]=tv.z; tcn[2]=tv.y; tcn[3]=tv.x; }
      else    { icn[0]=iv.x; icn[1]=iv.y; icn[2]=iv.z; icn[3]=iv.w;
                tcn[0]=tv.x; tcn[1]=tv.y; tcn[2]=tv.z; tcn[3]=tv.w; }
    }
#pragma unroll
    for (int k = 0; k < 4; k++){
      const float4 g4 = Gb[k];
      // prefetch step c*4+k+2 (stale icn on last chunk: valid in-range idx, unused)
      {
        const int pidx = (k==0) ? ic[2] : (k==1) ? ic[3] : (k==2) ? icn[0] : icn[1];
        Gb[(k+2)&3] = pG[(size_t)pidx * H];
      }

      const float tcur = tc[k];
      const float dtv = fmaxf(tcur - prev, 0.f); prev = tcur;

      f32x2 aR, aZ, aN;
      aR.x = fmaf(Wrd, dtv, g4.x); aR.y = 0.f;
      aZ.x = fmaf(Wzd, dtv, g4.y); aZ.y = 0.f;
      aN.x = bhn;                  aN.y = 0.f;
#pragma unroll
      for (int j = 0; j < NP; j++){
        aR = __builtin_elementwise_fma(Urp[j], hp[j], aR);
        aZ = __builtin_elementwise_fma(Uzp[j], hp[j], aZ);
        aN = __builtin_elementwise_fma(Unp[j], hp[j], aN);
      }
      const float ar = aR.x + aR.y;        // already -log2e * (pre-activation)
      const float az = aZ.x + aZ.y;
      const float hn = aN.x + aN.y;        // already 2*log2e * (Un·h + bhn)
      const float an = fmaf(Wnd, dtv, (float)g4.z);

      const float ea = fexp2(ar), eb = fexp2(az);
      const float pa = 1.f + ea,  pb = 1.f + eb;
      const float inv = frcp(pa * pb);     // shared rcp: r = 1/pa, z = 1/pb
      const float r = pb * inv;
      const float z = pa * inv;
      const float ec = fexp2(fmaf(r, hn, an));
      const float n  = fmaf(-2.f, frcp(1.f + ec), 1.f);
      hmine = fmaf(z, hmine - n, n);       // (1-z)*n + z*h

      hbuf[gb + li] = hmine;               // publish own element
      __builtin_amdgcn_wave_barrier();
      asm volatile("" ::: "memory");       // in-order DS pipe: write lands before reads

      float4 h03 = *reinterpret_cast<const float4*>(&hbuf[gb]);
      float4 h47 = *reinterpret_cast<const float4*>(&hbuf[gb+4]);
      hp[0].x=h03.x; hp[0].y=h03.y; hp[1].x=h03.z; hp[1].y=h03.w;
      hp[2].x=h47.x; hp[2].y=h47.y; hp[3].x=h47.z; hp[3].y=h47.w;
      if constexpr (H == 9){
        hp[4].x = hbuf[gb+8]; hp[4].y = hbuf[gb+9];   // [gb+9] zeroed pad, weight 0
      } else {
        float4 h8b = *reinterpret_cast<const float4*>(&hbuf[gb+8]);
        hp[4].x=h8b.x; hp[4].y=h8b.y; hp[5].x=h8b.z; hp[5].y=h8b.w; // [gb+11] pad, weight 0
      }
    }
#pragma unroll
    for (int k2 = 0; k2 < 4; k2++){ ic[k2] = icn[k2]; tc[k2] = tcn[k2]; }
  }

  // one atomic per sequence (lane 0 holds full h in hp pairs)
  if (li == 0){
    float dot = 0.f;
#pragma unroll
    for (int j = 0; j < NP; j++){
      dot = fmaf(fc_w[dir*H + 2*j], hp[j].x, dot);
      if (2*j + 1 < H) dot = fmaf(fc_w[dir*H + 2*j + 1], hp[j].y, dot);
    }
    atomicAdd(out + b, fc_all_w[tail_idx] * dot);
  }
}

__global__ __launch_bounds__(256) void gru_fused(
    const int* __restrict__ dp,  const float* __restrict__ dp_t,
    const int* __restrict__ cp,  const float* __restrict__ cp_t,
    const float4* __restrict__ Gdp, const float4* __restrict__ Gcp,
    const float* __restrict__ Wih_dpf, const float* __restrict__ Whh_dpf, const float* __restrict__ bhh_dpf,
    const float* __restrict__ Wih_dpb, const float* __restrict__ Whh_dpb, const float* __restrict__ bhh_dpb,
    const float* __restrict__ Wih_cpf, const float* __restrict__ Whh_cpf, const float* __restrict__ bhh_cpf,
    const float* __restrict__ Wih_cpb, const float* __restrict__ Whh_cpb, const float* __restrict__ bhh_cpb,
    const float* __restrict__ fc_dp_w, const float* __restrict__ fc_cp_w, const float* __restrict__ fc_all_w,
    float* __restrict__ out, int DP_BLOCKS)
{
  __shared__ __align__(16) float hbuf[28 * 20];
  if ((int)blockIdx.x < DP_BLOCKS){
    gru_body<9, 7, 4096>(blockIdx.x, dp, dp_t, Gdp,
        Wih_dpf, Whh_dpf, bhh_dpf, Wih_dpb, Whh_dpb, bhh_dpb,
        fc_dp_w, fc_all_w, 20, out, hbuf);
  } else {
    gru_body<11, 5, 10000>(blockIdx.x - DP_BLOCKS, cp, cp_t, Gcp,
        Wih_cpf, Whh_cpf, bhh_cpf, Wih_cpb, Whh_cpb, bhh_cpb,
        fc_cp_w, fc_all_w, 21, out, hbuf);
  }
}

extern "C" void kernel_launch(void* const* d_in, const int* in_sizes, int n_in,
                              void* d_out, int out_size, void* d_ws, size_t ws_size,
                              hipStream_t stream)
{
  const float* stat   = (const float*)d_in[0];
  const int*   dp     = (const int*)  d_in[1];
  const int*   cp     = (const int*)  d_in[2];
  const float* dp_t   = (const float*)d_in[3];
  const float* cp_t   = (const float*)d_in[4];
  const float* emb_dp = (const float*)d_in[5];
  const float* emb_cp = (const float*)d_in[6];

  const float* Wih_dpf = (const float*)d_in[7];
  const float* Whh_dpf = (const float*)d_in[8];
  const float* bih_dpf = (const float*)d_in[9];
  const float* bhh_dpf = (const float*)d_in[10];
  const float* Wih_dpb = (const float*)d_in[11];
  const float* Whh_dpb = (const float*)d_in[12];
  const float* bih_dpb = (const float*)d_in[13];
  const float* bhh_dpb = (const float*)d_in[14];
  const float* Wih_cpf = (const float*)d_in[15];
  const float* Whh_cpf = (const float*)d_in[16];
  const float* bih_cpf = (const float*)d_in[17];
  const float* bhh_cpf = (const float*)d_in[18];
  const float* Wih_cpb = (const float*)d_in[19];
  const float* Whh_cpb = (const float*)d_in[20];
  const float* bih_cpb = (const float*)d_in[21];
  const float* bhh_cpb = (const float*)d_in[22];

  const float* fc_dp_w  = (const float*)d_in[23];
  const float* fc_dp_b  = (const float*)d_in[24];
  const float* fc_cp_w  = (const float*)d_in[25];
  const float* fc_cp_b  = (const float*)d_in[26];
  const float* fc_all_w = (const float*)d_in[27];
  const float* fc_all_b = (const float*)d_in[28];

  float* out = (float*)d_out;

  // workspace: dp table (2*4096*9 float4 = 1.18 MB), cp table (2*10000*11 float4 = 3.52 MB)
  float4* Gdp = (float4*)d_ws;
  float4* Gcp = (float4*)((char*)d_ws + (size_t)(2*4096*9) * sizeof(float4));

  {
    const int total = 2*4096*9 + 2*10000*11 + 4096;
    const int blocks = (total + 255) / 256;
    pre_kernel<<<blocks, 256, 0, stream>>>(
        emb_dp, emb_cp,
        Wih_dpf, bih_dpf, bhh_dpf, Wih_dpb, bih_dpb, bhh_dpb,
        Wih_cpf, bih_cpf, bhh_cpf, Wih_cpb, bih_cpb, bhh_cpb,
        stat, fc_all_w, fc_all_b, fc_dp_b, fc_cp_b,
        Gdp, Gcp, out);
  }

  {
    const int DP_BLOCKS = (8192 + 27) / 28;   // H=9,  7 groups/wave
    const int CP_BLOCKS = (8192 + 19) / 20;   // H=11, 5 groups/wave
    gru_fused<<<DP_BLOCKS + CP_BLOCKS, 256, 0, stream>>>(
        dp, dp_t, cp, cp_t, Gdp, Gcp,
        Wih_dpf, Whh_dpf, bhh_dpf, Wih_dpb, Whh_dpb, bhh_dpb,
        Wih_cpf, Whh_cpf, bhh_cpf, Wih_cpb, Whh_cpb, bhh_cpb,
        fc_dp_w, fc_cp_w, fc_all_w, out, DP_BLOCKS);
  }
}